// Round 5
// baseline (835.780 us; speedup 1.0000x reference)
//
#include <hip/hip_runtime.h>

// WKV7 recurrence, T=4096, H=32, N=64, fp32.
// R10 post-mortem: stall/step identical to R8 (~150cy) — the prefetch-side
// nwa=nw*sA mul consumed ds_reads issued the same iteration (lgkm stall
// ~120cy/step), and per-step shared overhead (5 LDS reads + rotation) was
// paid per wave with only 2 lockstep waves/SIMD.
// R11: TWO ROWS PER WAVE. 4 waves x 256 threads, same 8-rows-of-one-head
// block geometry -> 256 blocks = 1 block/CU, 1 wave/SIMD. Shared per-step
// work (w,a,b,k,r,sc LDS reads, lw*la / lw*lr muls) paid ONCE for 2 rows;
// 4 reduce chains (Qa,Qr x 2 rows) interleaved in one wave_sum4 block:
// 4 chains x 2cy/stage covers the DPP hazard window -> no s_nops, block is
// issue-saturated. Prefetch loads raw; lwa/lwr computed from regs loaded a
// full iteration earlier (~130cy slack > LDS latency). R9/R10 algebra kept:
//   sa_{t+1} = Qa_t + sa_t*BA_t + v_t*KA_t, Qa_t = sum(s_{t-1} * w_t*a_{t+1})
//   x_t      = Qr_t + sa_t*BR_t + v_t*KR_t, Qr_t = sum(s_{t-1} * w_t*r_t)
// with BA/KA/BR/KR from the wkv7_pre pass, reduce consumed 1 iter after issue.

static constexpr int T_LEN = 4096;
static constexpr int H_HEADS = 32;
static constexpr int N_DIM = 64;
static constexpr int HN = H_HEADS * N_DIM;                 // 2048
static constexpr int WPB = 4;                              // waves/block
static constexpr int RPW = 2;                              // rows/wave
static constexpr int RPB = WPB * RPW;                      // 8 rows/block
static constexpr int BT = WPB * 64;                        // 256 threads
static constexpr int NB = HN / RPB;                        // 256 blocks
static constexpr int C = 16;                               // steps/chunk
static constexpr int TC = T_LEN / C;                       // 256 chunks

// ---- raw buffer load: SGPR soffset, OOB-safe (returns 0) ----
typedef int int32x4_t __attribute__((ext_vector_type(4)));
__device__ float llvm_amdgcn_raw_buffer_load_fp32(int32x4_t srsrc, int voffset,
                                                  int soffset, int glc_slc)
    __asm("llvm.amdgcn.raw.buffer.load.f32");

__device__ __forceinline__ int32x4_t make_srd(const void* p, unsigned bytes) {
  int32x4_t r;
  r.x = (int)(unsigned long long)p;
  r.y = (int)((unsigned long long)p >> 32); // stride=0 -> raw
  r.z = (int)bytes;                         // num_records
  r.w = 0x00020000;                         // raw dword
  return r;
}

// ---- paired 64-lane sums (pre-pass + prologue) ----
__device__ __forceinline__ void wave_sum2(float& x, float& y) {
  asm volatile(
      "s_nop 1\n\t"
      "v_add_f32 %0, %0, %0 row_shr:1 bound_ctrl:0\n\t"
      "v_add_f32 %1, %1, %1 row_shr:1 bound_ctrl:0\n\t"
      "s_nop 0\n\t"
      "v_add_f32 %0, %0, %0 row_shr:2 bound_ctrl:0\n\t"
      "v_add_f32 %1, %1, %1 row_shr:2 bound_ctrl:0\n\t"
      "s_nop 0\n\t"
      "v_add_f32 %0, %0, %0 row_shr:4 bound_ctrl:0\n\t"
      "v_add_f32 %1, %1, %1 row_shr:4 bound_ctrl:0\n\t"
      "s_nop 0\n\t"
      "v_add_f32 %0, %0, %0 row_shr:8 bound_ctrl:0\n\t"
      "v_add_f32 %1, %1, %1 row_shr:8 bound_ctrl:0\n\t"
      "s_nop 0\n\t"
      "v_add_f32 %0, %0, %0 row_bcast:15 row_mask:0xa\n\t"
      "v_add_f32 %1, %1, %1 row_bcast:15 row_mask:0xa\n\t"
      "s_nop 0\n\t"
      "v_add_f32 %0, %0, %0 row_bcast:31 row_mask:0xc\n\t"
      "v_add_f32 %1, %1, %1 row_bcast:31 row_mask:0xc\n\t"
      "s_nop 1\n\t"
      : "+v"(x), "+v"(y));
}

// ---- quad 64-lane sums: 4 independent chains interleaved. Each stage of a
// chain is separated by 3 other-chain ops (6cy) >= the 2-wait-state DPP
// hazard -> no per-stage s_nops needed. Result in lane 63 of each operand.
__device__ __forceinline__ void wave_sum4(float& x, float& y, float& z,
                                          float& w) {
  asm volatile(
      "s_nop 1\n\t"
      "v_add_f32 %0, %0, %0 row_shr:1 bound_ctrl:0\n\t"
      "v_add_f32 %1, %1, %1 row_shr:1 bound_ctrl:0\n\t"
      "v_add_f32 %2, %2, %2 row_shr:1 bound_ctrl:0\n\t"
      "v_add_f32 %3, %3, %3 row_shr:1 bound_ctrl:0\n\t"
      "v_add_f32 %0, %0, %0 row_shr:2 bound_ctrl:0\n\t"
      "v_add_f32 %1, %1, %1 row_shr:2 bound_ctrl:0\n\t"
      "v_add_f32 %2, %2, %2 row_shr:2 bound_ctrl:0\n\t"
      "v_add_f32 %3, %3, %3 row_shr:2 bound_ctrl:0\n\t"
      "v_add_f32 %0, %0, %0 row_shr:4 bound_ctrl:0\n\t"
      "v_add_f32 %1, %1, %1 row_shr:4 bound_ctrl:0\n\t"
      "v_add_f32 %2, %2, %2 row_shr:4 bound_ctrl:0\n\t"
      "v_add_f32 %3, %3, %3 row_shr:4 bound_ctrl:0\n\t"
      "v_add_f32 %0, %0, %0 row_shr:8 bound_ctrl:0\n\t"
      "v_add_f32 %1, %1, %1 row_shr:8 bound_ctrl:0\n\t"
      "v_add_f32 %2, %2, %2 row_shr:8 bound_ctrl:0\n\t"
      "v_add_f32 %3, %3, %3 row_shr:8 bound_ctrl:0\n\t"
      "v_add_f32 %0, %0, %0 row_bcast:15 row_mask:0xa\n\t"
      "v_add_f32 %1, %1, %1 row_bcast:15 row_mask:0xa\n\t"
      "v_add_f32 %2, %2, %2 row_bcast:15 row_mask:0xa\n\t"
      "v_add_f32 %3, %3, %3 row_bcast:15 row_mask:0xa\n\t"
      "v_add_f32 %0, %0, %0 row_bcast:31 row_mask:0xc\n\t"
      "v_add_f32 %1, %1, %1 row_bcast:31 row_mask:0xc\n\t"
      "v_add_f32 %2, %2, %2 row_bcast:31 row_mask:0xc\n\t"
      "v_add_f32 %3, %3, %3 row_bcast:31 row_mask:0xc\n\t"
      "s_nop 1\n\t"
      : "+v"(x), "+v"(y), "+v"(z), "+v"(w));
}

__device__ __forceinline__ float rl63(float v) {
  return __int_as_float(__builtin_amdgcn_readlane(__float_as_int(v), 63));
}

// ---- pre-pass: input-only cross scalars per (h,t):
//   BA = sum(b_t*a_{t+1}), KA = sum(k_t*a_{t+1}),
//   BR = sum(b_t*r_t),     KR = sum(k_t*r_t)   -> scw[h][t][4]
__global__ __launch_bounds__(256) void wkv7_pre(
    const float* __restrict__ rp, const float* __restrict__ kp,
    const float* __restrict__ ap, const float* __restrict__ bp,
    float* __restrict__ scw) {
  const int tid  = threadIdx.x;
  const int lane = tid & 63;
  const int wv   = tid >> 6;
  const int wid  = blockIdx.x * 4 + wv;     // 0..T*H-1
  const int t    = wid >> 5;                // 0..4095
  const int h    = wid & 31;
  const int hb   = h * N_DIM;

  constexpr unsigned ARR_BYTES = (unsigned)T_LEN * HN * 4u;
  const int32x4_t srd_r = make_srd(rp, ARR_BYTES);
  const int32x4_t srd_k = make_srd(kp, ARR_BYTES);
  const int32x4_t srd_a = make_srd(ap, ARR_BYTES);
  const int32x4_t srd_b = make_srd(bp, ARR_BYTES);

  const int vo    = lane << 2;
  const int so_t  = (t * HN + hb) << 2;
  const int so_t1 = ((t + 1) * HN + hb) << 2;   // t=T-1 -> OOB -> 0

  const float bv = llvm_amdgcn_raw_buffer_load_fp32(srd_b, vo, so_t, 0);
  const float kv = llvm_amdgcn_raw_buffer_load_fp32(srd_k, vo, so_t, 0);
  const float rv = llvm_amdgcn_raw_buffer_load_fp32(srd_r, vo, so_t, 0);
  const float a1 = llvm_amdgcn_raw_buffer_load_fp32(srd_a, vo, so_t1, 0);

  float pba = bv * a1, pka = kv * a1;
  float pbr = bv * rv, pkr = kv * rv;
  wave_sum4(pba, pka, pbr, pkr);
  if (lane == 63) {
    float4 o;
    o.x = pba; o.y = pka; o.z = pbr; o.w = pkr;
    *(float4*)(scw + ((size_t)h * T_LEN + t) * 4) = o;
  }
}

__global__ __launch_bounds__(BT, 1) void wkv7_scan(
    const float* __restrict__ rp, const float* __restrict__ wp,
    const float* __restrict__ kp, const float* __restrict__ vp,
    const float* __restrict__ ap, const float* __restrict__ bp,
    const float* __restrict__ s0p, float* __restrict__ xp,
    float* __restrict__ sop, const float* __restrict__ scp_g) {
  const int tid  = threadIdx.x;
  const int lane = tid & 63;
  const int wv   = tid >> 6;                 // 0..3
  const int blk  = blockIdx.x;
  const int h     = blk & (H_HEADS - 1);
  const int ibase = (blk >> 5) * RPB;        // 8 rows per block (as before)
  const int i0    = ibase + 2 * wv;          // this wave's two rows
  const int i1    = i0 + 1;
  const int hb    = h * N_DIM;

  // [buf][step][channel]: read addr = lane*4 + imm -> conflict-free.
  // sA holds a SHIFTED one step: sA[bi][u] = a[c*16+u+1].
  __shared__ float sw[2][C][N_DIM], sA[2][C][N_DIM], sB[2][C][N_DIM],
                   sK[2][C][N_DIM], sR[2][C][N_DIM];
  __shared__ __align__(8) float sV[2][C][RPB];
  __shared__ __align__(16) float sSC[2][C * 4];   // {BA,KA,BR,KR} per step
  __shared__ float xbuf[RPB][65];

  constexpr unsigned ARR_BYTES = (unsigned)T_LEN * HN * 4u;
  constexpr unsigned SC_BYTES  = (unsigned)T_LEN * H_HEADS * 4u * 4u; // 2MB
  const int32x4_t srd_r = make_srd(rp, ARR_BYTES);
  const int32x4_t srd_w = make_srd(wp, ARR_BYTES);
  const int32x4_t srd_k = make_srd(kp, ARR_BYTES);
  const int32x4_t srd_v = make_srd(vp, ARR_BYTES);
  const int32x4_t srd_a = make_srd(ap, ARR_BYTES);
  const int32x4_t srd_b = make_srd(bp, ARR_BYTES);
  const int32x4_t srd_c = make_srd(scp_g, SC_BYTES);

  float s1 = s0p[(size_t)(hb + i0) * N_DIM + lane];
  float s2 = s0p[(size_t)(hb + i1) * N_DIM + lane];
  const float a0v = ap[hb + lane];               // a_0 for the sa_0 prologue

  // staging: each thread covers (u0+4p, j), p=0..3, for 5 arrays
  const int j   = lane;
  const int u0  = tid >> 6;                       // 0..3
  const int vo0 = (u0 * HN + j) << 2;             // pass-0 voffset (bytes)
  const int sbase = hb << 2;
  // v staging: tids 0..127: u=tid>>3 (0..15), q=tid&7 (8 rows)
  const int uv  = tid >> 3;
  const int qv  = tid & 7;
  const int vov = (uv * HN + qv) << 2;
  const int svbase = (hb + ibase) << 2;
  // sc staging: wave 2, 64 contiguous floats per chunk from scw[h][c*16..]
  const int voc = lane << 2;
  const int scbase = h * (T_LEN * 16);            // bytes: h*T*4floats*4B

  float gw[4], ga[4], gb[4], gk[4], gr[4], gv, gsc;

#define STAGE_LOAD(CI)                                                     \
  do {                                                                     \
    const int so = (CI) * (C * HN * 4) + sbase;                            \
    _Pragma("unroll")                                                      \
    for (int p = 0; p < 4; ++p) {                                          \
      const int vop = vo0 + p * ((4 * HN) << 2);                           \
      gw[p] = llvm_amdgcn_raw_buffer_load_fp32(srd_w, vop, so, 0);         \
      ga[p] = llvm_amdgcn_raw_buffer_load_fp32(srd_a, vop, so + (HN << 2), 0); \
      gb[p] = llvm_amdgcn_raw_buffer_load_fp32(srd_b, vop, so, 0);         \
      gk[p] = llvm_amdgcn_raw_buffer_load_fp32(srd_k, vop, so, 0);         \
      gr[p] = llvm_amdgcn_raw_buffer_load_fp32(srd_r, vop, so, 0);         \
    }                                                                      \
    if (tid < 128)                                                         \
      gv = llvm_amdgcn_raw_buffer_load_fp32(                               \
          srd_v, vov, (CI) * (C * HN * 4) + svbase, 0);                    \
    if (wv == 2)                                                           \
      gsc = llvm_amdgcn_raw_buffer_load_fp32(                              \
          srd_c, voc, (CI) * (C * 16) + scbase, 0);                        \
  } while (0)

#define STAGE_STORE(BI)                                                    \
  do {                                                                     \
    _Pragma("unroll")                                                      \
    for (int p = 0; p < 4; ++p) {                                          \
      sw[BI][u0 + 4 * p][j] = gw[p];                                       \
      sA[BI][u0 + 4 * p][j] = ga[p];                                       \
      sB[BI][u0 + 4 * p][j] = gb[p];                                       \
      sK[BI][u0 + 4 * p][j] = gk[p];                                       \
      sR[BI][u0 + 4 * p][j] = gr[p];                                       \
    }                                                                      \
    if (tid < 128) sV[BI][uv][qv] = gv;                                    \
    if (wv == 2) sSC[BI][lane] = gsc;                                      \
  } while (0)

  float xacc0 = 0.0f, xacc1 = 0.0f;

  STAGE_LOAD(0);
  STAGE_STORE(0);
  // prologue: sa_0 = sum(s_init * a_0) per row — only unpaired reductions
  float sa0, sa1;
  {
    float p0 = s1 * a0v, p1 = s2 * a0v;
    wave_sum2(p0, p1);
    sa0 = rl63(p0);
    sa1 = rl63(p1);
  }
  __syncthreads();

  // in-flight reduce regs (consumed one iteration after issue) + their
  // recomposition operands
  float qpq0 = 0.0f, qpx0 = 0.0f, qpq1 = 0.0f, qpx1 = 0.0f;
  float2 lvp; lvp.x = lvp.y = 0.0f;
  float4 scp; scp.x = scp.y = scp.z = scp.w = 0.0f;

  for (int c = 0; c < TC; ++c) {
    const int bi = c & 1;

    STAGE_LOAD(c + 1);              // global loads fly under compute
    __builtin_amdgcn_sched_barrier(0);

    // one-step RAW LDS prefetch (values multiplied only next iteration)
    float lw = sw[bi][0][lane], la = sA[bi][0][lane], lb = sB[bi][0][lane],
          lk = sK[bi][0][lane], lr = sR[bi][0][lane];
    float2 lv = *(const float2*)&sV[bi][0][2 * wv];
    float4 scv = *(const float4*)&sSC[bi][0];
#pragma unroll
    for (int u = 0; u < C; ++u) {
      const int un = (u < C - 1) ? u + 1 : u;  // compile-time per iter
      const float nw = sw[bi][un][lane], na = sA[bi][un][lane],
                  nb = sB[bi][un][lane], nk = sK[bi][un][lane],
                  nr = sR[bi][un][lane];
      const float2 nv = *(const float2*)&sV[bi][un][2 * wv];
      const float4 nscv = *(const float4*)&sSC[bi][un * 4];

      // shared muls, operands loaded >=1 iteration ago -> no lgkm stall
      const float lwa = lw * la;    // w_t * a_{t+1}
      const float lwr = lw * lr;    // w_t * r_t

      // 1. issue reduce_t over s_{t-1} for both rows (4 chains)
      float pq0 = s1 * lwa, px0 = s1 * lwr;
      float pq1 = s2 * lwa, px1 = s2 * lwr;
      wave_sum4(pq0, px0, pq1, px1);

      // 2. consume reduce_{t-1} (issued a full iteration ago; no stall)
      if (u >= 1) {
        const float Qa0 = rl63(qpq0), Qr0 = rl63(qpx0);
        const float Qa1 = rl63(qpq1), Qr1 = rl63(qpx1);
        const float xv0 = fmaf(sa0, scp.z, fmaf(lvp.x, scp.w, Qr0));
        sa0             = fmaf(sa0, scp.x, fmaf(lvp.x, scp.y, Qa0));
        const float xv1 = fmaf(sa1, scp.z, fmaf(lvp.y, scp.w, Qr1));
        sa1             = fmaf(sa1, scp.x, fmaf(lvp.y, scp.y, Qa1));
        const int tl = ((c & 3) << 4) | (u - 1);
        xacc0 = (lane == tl) ? xv0 : xacc0;
        xacc1 = (lane == tl) ? xv1 : xacc1;
      }
      // (u==0: sa already produced by previous chunk's epilogue / prologue)

      // 3. state update (1-deep chains from sa)
      s1 = fmaf(s1, lw, fmaf(sa0, lb, lv.x * lk));
      s2 = fmaf(s2, lw, fmaf(sa1, lb, lv.y * lk));

      qpq0 = pq0; qpx0 = px0; qpq1 = pq1; qpx1 = px1;
      lvp = lv; scp = scv;
      lw = nw; la = na; lb = nb; lk = nk; lr = nr; lv = nv; scv = nscv;
    }

    // chunk epilogue: drain reduce for t = c*16+15 (keeps x-store grouping)
    {
      const float Qa0 = rl63(qpq0), Qr0 = rl63(qpx0);
      const float Qa1 = rl63(qpq1), Qr1 = rl63(qpx1);
      const float xv0 = fmaf(sa0, scp.z, fmaf(lvp.x, scp.w, Qr0));
      sa0             = fmaf(sa0, scp.x, fmaf(lvp.x, scp.y, Qa0));
      const float xv1 = fmaf(sa1, scp.z, fmaf(lvp.y, scp.w, Qr1));
      sa1             = fmaf(sa1, scp.x, fmaf(lvp.y, scp.y, Qa1));
      const int tl = ((c & 3) << 4) | 15;
      xacc0 = (lane == tl) ? xv0 : xacc0;
      xacc1 = (lane == tl) ? xv1 : xacc1;
    }

    __builtin_amdgcn_sched_barrier(0);
    STAGE_STORE(bi ^ 1);            // vmcnt wait lands here, after compute
    __syncthreads();

    if ((c & 3) == 3) {
      // 64 steps complete: transpose through LDS -> coalesced stores
      xbuf[2 * wv][lane]     = xacc0;
      xbuf[2 * wv + 1][lane] = xacc1;
      __syncthreads();
      const int iw = tid & 7;
      const int tb = tid >> 3;      // 0..31
      const int t0 = (c + 1) * C - 64;
      xp[(size_t)(t0 + tb) * HN + hb + ibase + iw]      = xbuf[iw][tb];
      xp[(size_t)(t0 + tb + 32) * HN + hb + ibase + iw] = xbuf[iw][tb + 32];
      // no trailing barrier needed: next xbuf write is 4 chunk-barriers away
    }
  }

#undef STAGE_LOAD
#undef STAGE_STORE

  sop[(size_t)(hb + i0) * N_DIM + lane] = s1;
  sop[(size_t)(hb + i1) * N_DIM + lane] = s2;
}

extern "C" void kernel_launch(void* const* d_in, const int* in_sizes, int n_in,
                              void* d_out, int out_size, void* d_ws, size_t ws_size,
                              hipStream_t stream) {
  // setup_inputs order: seq_length(int,1), r, w, k, v, a, b, state2
  const float* r  = (const float*)d_in[1];
  const float* w  = (const float*)d_in[2];
  const float* k  = (const float*)d_in[3];
  const float* v  = (const float*)d_in[4];
  const float* a  = (const float*)d_in[5];
  const float* b  = (const float*)d_in[6];
  const float* s0 = (const float*)d_in[7];
  float* x    = (float*)d_out;                       // [T,H,1,N] flat
  float* sout = x + (size_t)T_LEN * H_HEADS * N_DIM; // [H,N,N]
  float* scw  = (float*)d_ws;                        // 2MB: [H][T][4] scalars

  wkv7_pre<<<dim3(T_LEN * H_HEADS / 4), dim3(256), 0, stream>>>(r, k, a, b, scw);
  wkv7_scan<<<dim3(NB), dim3(BT), 0, stream>>>(r, w, k, v, a, b, s0, x, sout, scw);
}